// Round 12
// baseline (459.658 us; speedup 1.0000x reference)
//
#include <hip/hip_runtime.h>
#include <hip/hip_bf16.h>
#include <math.h>

typedef __hip_bfloat16 bf16;
typedef short bf16x8 __attribute__((ext_vector_type(8)));
typedef float f32x4 __attribute__((ext_vector_type(4)));

#define N_NODES 32768
#define D_DIM 128
#define E_EDG 262144
#define M_MOT 131072
#define NG_G 32
#define F_TOT 832
// P: Q2[0,128) K2[128,256) Q3[256,512) K3[512,768) S_mem[768,832)
// dP: dQ2 dK2 dQ3 dK3 Pm ; -0.125*Km@W_Qm folded into bwd B-frags
// lam2=1 lam3=0.5 lamm=1 b2=b3=bm=1 ; no-max softmax, z as reciprocal
// bwd GEMM split: pass1 K-tiles {0..3,8..15,24,25} (dQ2/dQ3/Pm, ready after fused_c)
//                 pass2 K-tiles {4..7,16..23}     (dK2/dK3, ready after phaseE)
#define BWD_MASK1 0x0300FF0Fu
#define BWD_MASK2 0x00FF00F0u

__device__ __forceinline__ float wsum64(float v){
#pragma unroll
  for (int o = 32; o > 0; o >>= 1) v += __shfl_xor(v, o, 64);
  return v;
}
__device__ __forceinline__ float hsum32(float v){
#pragma unroll
  for (int o = 16; o > 0; o >>= 1) v += __shfl_xor(v, o, 64);
  return v;
}
__device__ __forceinline__ float hmax32(float v){
#pragma unroll
  for (int o = 16; o > 0; o >>= 1) v = fmaxf(v, __shfl_xor(v, o, 64));
  return v;
}
__device__ __forceinline__ float hsum8(float v){
#pragma unroll
  for (int o = 4; o > 0; o >>= 1) v += __shfl_xor(v, o, 64);
  return v;
}
__device__ __forceinline__ float bflo(unsigned u){ return __uint_as_float(u << 16); }
__device__ __forceinline__ float bfhi(unsigned u){ return __uint_as_float(u & 0xffff0000u); }
__device__ __forceinline__ unsigned packbf(float x, float y){
  bf16 a = __float2bfloat16(x), b = __float2bfloat16(y);
  unsigned short ua = *(unsigned short*)&a, ub = *(unsigned short*)&b;
  return (unsigned)ua | ((unsigned)ub << 16);
}
__device__ __forceinline__ void unpk8(uint4 p, float* f){
  f[0] = bflo(p.x); f[1] = bfhi(p.x); f[2] = bflo(p.y); f[3] = bfhi(p.y);
  f[4] = bflo(p.z); f[5] = bfhi(p.z); f[6] = bflo(p.w); f[7] = bfhi(p.w);
}

// masked-K bwd GEMM body: dG[n,d] (+)= sum_{f in mask tiles} dP[n,f]*B[f,d]
__device__ __forceinline__ void bwd_body(const bf16* dP, const bf16* wfB, float* dG,
                                         unsigned mask, bool accum, int b, int tid){
  int wave = tid >> 6, lane = tid & 63;
  int m0 = b * 64 + wave * 16;
  int rw = lane & 15, quad = lane >> 4;
  const bf16* aptr = dP + (size_t)(m0 + rw) * F_TOT + quad * 8;
  f32x4 acc[8];
#pragma unroll
  for (int i = 0; i < 8; i++) acc[i] = (f32x4){0.f, 0.f, 0.f, 0.f};
  for (int kt = 0; kt < 26; kt++){
    if (!((mask >> kt) & 1u)) continue;
    bf16x8 a = *(const bf16x8*)(aptr + kt * 32);
#pragma unroll
    for (int td = 0; td < 8; td++){
      bf16x8 bb = *(const bf16x8*)(wfB + (((size_t)td * 26 + kt) * 64 + lane) * 8);
      acc[td] = __builtin_amdgcn_mfma_f32_16x16x32_bf16(a, bb, acc[td], 0, 0, 0);
    }
  }
#pragma unroll
  for (int td = 0; td < 8; td++){
    int col = td * 16 + rw;
#pragma unroll
    for (int r = 0; r < 4; r++){
      int row = m0 + quad * 4 + r;
      if (accum) dG[(size_t)row * 128 + col] += acc[td][r];
      else       dG[(size_t)row * 128 + col]  = acc[td][r];
    }
  }
}

// ================ PHASE A: hist | Wcat/Ttb prep | Mprod (Km in LDS) ================
__global__ __launch_bounds__(256) void k_phaseA(
    const int* c2, const int* u2, const int* c3, const int* u3, const int* v3,
    const float* wq2, const float* wk2, const float* wq3, const float* wk3,
    const float* wqm, const float* wkm, const float* bmem, const float* Ttau,
    int* cnt, float* Wcat, bf16* Ttb, float* Mprod){
  __shared__ float KmL[64];
  int b = blockIdx.x, t = threadIdx.x;
  if (b < 1024){
    int i = b * 256 + t;
    atomicAdd(&cnt[c2[i]], 1);
    atomicAdd(&cnt[N_NODES + u2[i]], 1);
    if (i < M_MOT){
      atomicAdd(&cnt[2 * N_NODES + c3[i]], 1);
      atomicAdd(&cnt[3 * N_NODES + u3[i]], 1);
      atomicAdd(&cnt[4 * N_NODES + v3[i]], 1);
    }
  } else if (b < 1440){
    int idx = (b - 1024) * 256 + t;
    if (idx < 768 * D_DIM){
      int f = idx / D_DIM, d = idx - f * D_DIM;
      const float* src; int fr;
      if      (f < 128){ src = wq2; fr = f; }
      else if (f < 256){ src = wk2; fr = f - 128; }
      else if (f < 512){ src = wq3; fr = f - 256; }
      else             { src = wk3; fr = f - 512; }
      Wcat[f * D_DIM + d] = src[fr * D_DIM + d];
    } else {
      int j = idx - 768 * D_DIM; // < 8192
      Ttb[j] = __float2bfloat16(Ttau[j]);
    }
  } else {
    int hk = b - 1440;            // 0..63
    int h = hk >> 5, k = hk & 31;
    if (t < 64){
      const float* wrow = wkm + (size_t)(h * 64 + t) * D_DIM;
      const float* brow = bmem + k * D_DIM;
      float acc = 0.f;
      for (int d = 0; d < D_DIM; d++) acc += wrow[d] * brow[d];
      KmL[t] = acc;
    }
    __syncthreads();
    if (t < 128){
      const float* w = wqm + (size_t)(h * 64) * 128 + t;
      float acc = 0.f;
      for (int z = 0; z < 64; z++) acc += w[z * 128] * KmL[z];
      Mprod[t * 64 + hk] = acc;
    }
  }
}

// ================ PHASE B: scan | layernorm (wave/node) | pack_frags ================
__global__ __launch_bounds__(1024) void k_phaseB(
    int* cntcur, int* off,
    const float* X, const float* gamma, const float* beta,
    bf16* Gb, float* mu, float* rstd, float* e_node,
    const float* Wcat, const float* Mprod, bf16* wfF, bf16* wfB){
  __shared__ int sd[1024];
  int b = blockIdx.x, t = threadIdx.x;
  if (b < 5){
    int a = b;
    int* c = cntcur + a * N_NODES;
    int* o = off + a * (N_NODES + 1);
    int loc[32];
    int sum = 0;
#pragma unroll
    for (int j = 0; j < 32; j++){ loc[j] = sum; sum += c[t * 32 + j]; }
    sd[t] = sum;
    __syncthreads();
    for (int s = 1; s < 1024; s <<= 1){
      int v = (t >= s) ? sd[t - s] : 0;
      __syncthreads();
      sd[t] += v;
      __syncthreads();
    }
    int excl = sd[t] - sum;
#pragma unroll
    for (int j = 0; j < 32; j++){
      int val = excl + loc[j];
      o[t * 32 + j] = val;
      c[t * 32 + j] = val;
    }
    if (t == 1023) o[N_NODES] = sd[1023];
  } else if (b < 2053){
    int wv = t >> 6, l = t & 63;
    int n = (b - 5) * 16 + wv;
    float2 x2 = ((const float2*)(X + (size_t)n * 128))[l];
    float sumx = wsum64(x2.x + x2.y);
    float sumxx = wsum64(x2.x * x2.x + x2.y * x2.y);
    float m = sumx * (1.0f / 128.0f);
    float var = sumxx * (1.0f / 128.0f) - m * m;
    float rs = rsqrtf(var + 1e-5f);
    float2 gg = ((const float2*)gamma)[l];
    float2 bb = ((const float2*)beta)[l];
    ((unsigned*)(Gb + (size_t)n * 128))[l] =
        packbf(gg.x * (x2.x - m) * rs + bb.x, gg.y * (x2.y - m) * rs + bb.y);
    if (l == 0){ mu[n] = m; rstd[n] = rs; e_node[n] = 0.5f * sumxx; }
  } else {
    int idx = (b - 2053) * 1024 + t;   // < 106496
    int j = idx & 7, lane = (idx >> 3) & 63, tt = idx >> 9;
    {
      int tn = tt >> 2, kt = tt & 3;
      int f = tn * 16 + (lane & 15), d = kt * 32 + (lane >> 4) * 8 + j;
      float v = (f < 768) ? Wcat[f * 128 + d] : 0.125f * Mprod[d * 64 + (f - 768)];
      wfF[idx] = __float2bfloat16(v);
    }
    {
      int td = tt / 26, tf = tt - td * 26;
      int f = tf * 32 + (lane >> 4) * 8 + j, d = td * 16 + (lane & 15);
      float v = (f < 768) ? Wcat[f * 128 + d] : -0.125f * Mprod[d * 64 + (f - 768)];
      wfB[idx] = __float2bfloat16(v);
    }
  }
}

// ================ PHASE C: fwd_mfma (13/15) | fill (2/15) interleaved ================
__global__ __launch_bounds__(256) void k_phaseC(
    const bf16* Gb, const bf16* wfF, bf16* P,
    const int* c2, const int* u2, const int* c3, const int* u3, const int* v3,
    const int* tt, const float* a2, int* cur,
    uint2* lec, uint2* leu, uint2* lmc, uint2* lmu, uint2* lmv){
  int b = blockIdx.x;
  int g = b / 15, r = b - g * 15;
  if (r < 13){
    int f = g * 13 + r;
    int bx = f & 511, by = f >> 9;
    int wave = threadIdx.x >> 6, lane = threadIdx.x & 63;
    int m0 = bx * 64 + wave * 16;
    int tn0 = by * 4;
    int rw = lane & 15, quad = lane >> 4;
    const bf16* aptr = Gb + (size_t)(m0 + rw) * 128 + quad * 8;
    bf16x8 a[4];
#pragma unroll
    for (int kt = 0; kt < 4; kt++) a[kt] = *(const bf16x8*)(aptr + kt * 32);
    f32x4 acc[4];
#pragma unroll
    for (int i = 0; i < 4; i++) acc[i] = (f32x4){0.f, 0.f, 0.f, 0.f};
#pragma unroll
    for (int nf = 0; nf < 4; nf++){
      int tn = tn0 + nf;
#pragma unroll
      for (int kt = 0; kt < 4; kt++){
        bf16x8 bb = *(const bf16x8*)(wfF + (((size_t)tn * 4 + kt) * 64 + lane) * 8);
        acc[nf] = __builtin_amdgcn_mfma_f32_16x16x32_bf16(a[kt], bb, acc[nf], 0, 0, 0);
      }
    }
#pragma unroll
    for (int nf = 0; nf < 4; nf++){
      int col = (tn0 + nf) * 16 + rw;
#pragma unroll
      for (int rr = 0; rr < 4; rr++){
        int row = m0 + quad * 4 + rr;
        P[(size_t)row * F_TOT + col] = __float2bfloat16(acc[nf][rr]);
      }
    }
  } else {
    int i = (g * 2 + (r - 13)) * 256 + threadIdx.x;
    {
      int c = c2[i], u = u2[i];
      int posc = atomicAdd(&cur[c], 1);
      float2 av = *(const float2*)(a2 + (size_t)i * 2);
      lec[posc] = make_uint2((unsigned)u, packbf(av.x, av.y));
      int posu = atomicAdd(&cur[N_NODES + u], 1);
      leu[posu] = make_uint2((unsigned)c, (unsigned)posc);
    }
    if (i < M_MOT){
      int c = c3[i], u = u3[i], v = v3[i], t = tt[i];
      int posc = atomicAdd(&cur[2 * N_NODES + c], 1);
      lmc[posc] = make_uint2((unsigned)(u | (v << 16)), (unsigned)t);
      int posu = atomicAdd(&cur[3 * N_NODES + u], 1);
      lmu[posu] = make_uint2((unsigned)c, (unsigned)posc);
      int posv = atomicAdd(&cur[4 * N_NODES + v], 1);
      lmv[posv] = make_uint2((unsigned)(c | (t << 16)), (unsigned)posc);
    }
  }
}

// ================ PHASE D: fused forward gathers ================
__global__ __launch_bounds__(256) void k_fused_c(const bf16* P, const uint2* lec, const uint2* lmc,
                   const bf16* Ttb, const int* off_ec, const int* off_mc,
                   float* s2, float* rz2, float* s3, float* qkb, float* tvb, float* rz3,
                   bf16* dP, float* e_pair, float* e_mot, float* e_mem){
  int b = blockIdx.x;
  int type = b % 3, grp = b / 3;
  int wave = threadIdx.x >> 6, z = threadIdx.x & 63;
  int n = grp * 4 + wave;
  int l = z & 31, lh = z >> 5;

  if (type == 0){
    // ---- edges: 4 per wave (16-lane groups), 8-lane head sub-groups ----
    int q = z >> 4, l16 = z & 15, hg = l16 >> 3;
    int beg = off_ec[n], end = off_ec[n + 1];
    uint4 qp = ((const uint4*)(P + (size_t)n * F_TOT))[l16];
    float qv[8]; unpk8(qp, qv);
    float acc[8] = {0,0,0,0,0,0,0,0};
    float zz = 0.f;
    int iters = (end - beg + 3) >> 2;
    for (int it = 0; it < iters; it++){
      int idx = beg + 4 * it + q;
      bool valid = idx < end;
      int idc = valid ? idx : end - 1;
      uint2 pl = lec[idc];
      uint4 kp = ((const uint4*)(P + (size_t)pl.x * F_TOT + 128))[l16];
      float kv[8]; unpk8(kp, kv);
      float d = 0.f;
#pragma unroll
      for (int j = 0; j < 8; j++) d += qv[j] * kv[j];
      float s = hsum8(d) * 0.125f + (hg ? bfhi(pl.y) : bflo(pl.y));
      if (valid && (l16 & 7) == 0) s2[2 * idx + hg] = s;
      float ex = valid ? expf(s) : 0.f;
#pragma unroll
      for (int j = 0; j < 8; j++) acc[j] += ex * kv[j];
      zz += ex;
    }
#pragma unroll
    for (int j = 0; j < 8; j++){
      acc[j] += __shfl_xor(acc[j], 16, 64);
      acc[j] += __shfl_xor(acc[j], 32, 64);
    }
    zz += __shfl_xor(zz, 16, 64);
    zz += __shfl_xor(zz, 32, 64);
    float rz = (zz > 0.f) ? 1.0f / zz : 0.f;
    float coef = -0.125f * rz;
    if (z < 16){
      uint4 o;
      o.x = packbf(coef * acc[0], coef * acc[1]);
      o.y = packbf(coef * acc[2], coef * acc[3]);
      o.z = packbf(coef * acc[4], coef * acc[5]);
      o.w = packbf(coef * acc[6], coef * acc[7]);
      ((uint4*)(dP + (size_t)n * F_TOT))[l16] = o;
      if ((l16 & 7) == 0) rz2[n * 2 + hg] = rz;
    }
    float eterm = (zz > 0.f) ? -logf(zz) : 0.f;   // lam2 = 1
    float eo = __shfl(eterm, 8, 64);
    if (z == 0) e_pair[n] = eterm + eo;
  } else if (type == 1){
    // ---- motifs: 2 per wave (32-lane halves), 8-lane hr groups ----
    int g = l >> 3, hg = g >> 1;
    int beg = off_mc[n], end = off_mc[n + 1];
    uint4 qp = ((const uint4*)(P + (size_t)n * F_TOT + 256))[l];
    float qv[8]; unpk8(qp, qv);
    float acc[8] = {0,0,0,0,0,0,0,0};
    float zz = 0.f;
    int iters = (end - beg + 1) >> 1;
    for (int it = 0; it < iters; it++){
      int idx = beg + 2 * it + lh;
      bool valid = idx < end;
      int idc = valid ? idx : end - 1;
      uint2 pl = lmc[idc];
      int u = pl.x & 0xffff, v = pl.x >> 16, t = pl.y;
      uint4 kup = ((const uint4*)(P + (size_t)u * F_TOT + 512))[l];
      uint4 kvp = ((const uint4*)(P + (size_t)v * F_TOT + 512))[l];
      uint4 tp  = ((const uint4*)(Ttb + (size_t)t * 256))[l];
      float k[8], vv[8], pt[8];
      unpk8(kup, k); unpk8(kvp, vv); unpk8(tp, pt);
      float dq = 0.f, dt = 0.f;
#pragma unroll
      for (int j = 0; j < 8; j++){ dq += qv[j] * k[j]; dt += pt[j] * vv[j]; }
      float qk = hsum8(dq);
      float tv = hsum8(dt);
      if (valid && (l & 7) == 0){ qkb[(size_t)4 * idx + g] = qk; tvb[(size_t)4 * idx + g] = tv; }
      float w = qk * tv;
      float s = (w + __shfl_xor(w, 8, 64)) * (1.0f / 64.0f);
      if (valid && (l & 15) == 0) s3[2 * idx + hg] = s;
      float ex = valid ? expf(s) : 0.f;
      float et = ex * tv;
#pragma unroll
      for (int j = 0; j < 8; j++) acc[j] += et * k[j];
      zz += ex;
    }
#pragma unroll
    for (int j = 0; j < 8; j++) acc[j] += __shfl_xor(acc[j], 32, 64);
    zz += __shfl_xor(zz, 32, 64);
    float rz = (zz > 0.f) ? 1.0f / zz : 0.f;
    float coef = (-0.5f / 64.0f) * rz;
    if (z < 32){
      uint4 o;
      o.x = packbf(coef * acc[0], coef * acc[1]);
      o.y = packbf(coef * acc[2], coef * acc[3]);
      o.z = packbf(coef * acc[4], coef * acc[5]);
      o.w = packbf(coef * acc[6], coef * acc[7]);
      ((uint4*)(dP + (size_t)n * F_TOT + 256))[l] = o;
      if ((l & 15) == 0) rz3[n * 2 + hg] = rz;
    }
    float eterm = (zz > 0.f) ? -0.5f * logf(zz) : 0.f;   // lam3 = 0.5
    float eo = __shfl(eterm, 16, 64);
    if (z == 0) e_mot[n] = eterm + eo;
  } else {
    unsigned short us = ((const unsigned short*)(P + (size_t)n * F_TOT + 768))[z];
    float s = __uint_as_float((unsigned)us << 16);
    float mx = hmax32(s);
    float ex = expf(s - mx);
    float se = hsum32(ex);
    float p = ex / se;
    bf16 pb = __float2bfloat16(p);
    ((unsigned short*)(dP + (size_t)n * F_TOT + 768))[z] = *(unsigned short*)&pb;
    float eterm = -(mx + logf(se));
    float eo = __shfl(eterm, z ^ 32, 64);
    if (z == 0) e_mem[n] = eterm + eo;   // lamm=1, bm=1
  }
}

// ================ PHASE E: bwd pass1 (512) | node_energy (128) | fused_uv ================
__global__ __launch_bounds__(256) void k_phaseE(const bf16* P, const uint2* leu,
                    const uint2* lmu, const uint2* lmv, const bf16* Ttb,
                    const float* s2, const float* rz2, const float* s3, const float* rz3,
                    const float* qkb, const float* tvb,
                    const int* off_eu, const int* off_mu, const int* off_mv, bf16* dP,
                    const float* e_node, const float* e_pair, const float* e_mot,
                    const float* e_mem, const int* batch, float* Eg,
                    const bf16* wfB, float* dG){
  __shared__ float eg[NG_G];
  int b = blockIdx.x;
  if (b < 512){
    bwd_body(dP, wfB, dG, BWD_MASK1, false, b, threadIdx.x);
    return;
  }
  if (b < 640){
    int t = threadIdx.x;
    if (t < NG_G) eg[t] = 0.f;
    __syncthreads();
    int n = (b - 512) * 256 + t;
    float e = e_node[n] + e_pair[n] + e_mot[n] + e_mem[n];
    atomicAdd(&eg[batch[n]], e);
    __syncthreads();
    if (t < NG_G) atomicAdd(&Eg[t], eg[t]);
    return;
  }
  int b2 = b - 640;
  int type = b2 & 1, grp = b2 >> 1;
  int wave = threadIdx.x >> 6, z = threadIdx.x & 63;
  int n = grp * 4 + wave;
  int l = z & 31, lh = z >> 5;

  if (type == 0){
    // dK2[u]: 4 edges per wave
    int q = z >> 4, l16 = z & 15, hg = l16 >> 3;
    int beg = off_eu[n], end = off_eu[n + 1];
    float acc[8] = {0,0,0,0,0,0,0,0};
    int iters = (end - beg + 3) >> 2;
    for (int it = 0; it < iters; it++){
      int idx = beg + 4 * it + q;
      bool valid = idx < end;
      int idc = valid ? idx : end - 1;
      uint2 pl = leu[idc];
      uint4 qp = ((const uint4*)(P + (size_t)pl.x * F_TOT))[l16];
      float qv[8]; unpk8(qp, qv);
      float p = valid ? expf(s2[2 * pl.y + hg]) * rz2[pl.x * 2 + hg] : 0.f;
#pragma unroll
      for (int j = 0; j < 8; j++) acc[j] += p * qv[j];
    }
#pragma unroll
    for (int j = 0; j < 8; j++){
      acc[j] += __shfl_xor(acc[j], 16, 64);
      acc[j] += __shfl_xor(acc[j], 32, 64);
    }
    if (z < 16){
      uint4 o;
      o.x = packbf(-0.125f * acc[0], -0.125f * acc[1]);
      o.y = packbf(-0.125f * acc[2], -0.125f * acc[3]);
      o.z = packbf(-0.125f * acc[4], -0.125f * acc[5]);
      o.w = packbf(-0.125f * acc[6], -0.125f * acc[7]);
      ((uint4*)(dP + (size_t)n * F_TOT + 128))[l16] = o;
    }
  } else {
    int g = l >> 3, hg = g >> 1;
    float acc[8] = {0,0,0,0,0,0,0,0};
    {
      int beg = off_mu[n], end = off_mu[n + 1];
      int iters = (end - beg + 1) >> 1;
      for (int it = 0; it < iters; it++){
        int idx = beg + 2 * it + lh;
        bool valid = idx < end;
        int idc = valid ? idx : end - 1;
        uint2 pl = lmu[idc];
        unsigned c = pl.x, posc = pl.y;
        uint4 qp = ((const uint4*)(P + (size_t)c * F_TOT + 256))[l];
        float qv[8]; unpk8(qp, qv);
        float w = valid ? expf(s3[2 * posc + hg]) * rz3[c * 2 + hg] * tvb[(size_t)4 * posc + g] : 0.f;
#pragma unroll
        for (int j = 0; j < 8; j++) acc[j] += w * qv[j];
      }
    }
    {
      int beg = off_mv[n], end = off_mv[n + 1];
      int iters = (end - beg + 1) >> 1;
      for (int it = 0; it < iters; it++){
        int idx = beg + 2 * it + lh;
        bool valid = idx < end;
        int idc = valid ? idx : end - 1;
        uint2 pl = lmv[idc];
        unsigned c = pl.x & 0xffff, t = pl.x >> 16, posc = pl.y;
        uint4 tp = ((const uint4*)(Ttb + (size_t)t * 256))[l];
        float pt[8]; unpk8(tp, pt);
        float w = valid ? expf(s3[2 * posc + hg]) * rz3[c * 2 + hg] * qkb[(size_t)4 * posc + g] : 0.f;
#pragma unroll
        for (int j = 0; j < 8; j++) acc[j] += w * pt[j];
      }
    }
#pragma unroll
    for (int j = 0; j < 8; j++) acc[j] += __shfl_xor(acc[j], 32, 64);
    const float cst = -0.5f / 64.0f;
    if (z < 32){
      uint4 o;
      o.x = packbf(cst * acc[0], cst * acc[1]);
      o.y = packbf(cst * acc[2], cst * acc[3]);
      o.z = packbf(cst * acc[4], cst * acc[5]);
      o.w = packbf(cst * acc[6], cst * acc[7]);
      ((uint4*)(dP + (size_t)n * F_TOT + 512))[l] = o;
    }
  }
}

// ================ PHASE F: bwd pass2 (dK2/dK3 tiles, accumulate) ================
__global__ __launch_bounds__(256) void k_bwd2(const bf16* dP, const bf16* wfB, float* dG){
  bwd_body(dP, wfB, dG, BWD_MASK2, true, blockIdx.x, threadIdx.x);
}

// ================ PHASE G: finalize (wave/node) + Eg write ================
__global__ __launch_bounds__(256) void k_finalize(const float* X, const float* dG, const float* gamma,
                    const float* mu, const float* rstd, const float* step_p,
                    const float* Eg, float* out){
  int wave = threadIdx.x >> 6, l = threadIdx.x & 63;
  int n = blockIdx.x * 4 + wave;
  float2 x2 = ((const float2*)(X + (size_t)n * 128))[l];
  float2 dg2 = ((const float2*)(dG + (size_t)n * 128))[l];
  float2 gg = ((const float2*)gamma)[l];
  float rs = rstd[n], m = mu[n];
  float xh0 = (x2.x - m) * rs, xh1 = (x2.y - m) * rs;
  float dxh0 = dg2.x * gg.x, dxh1 = dg2.y * gg.y;
  float s1 = wsum64(dxh0 + dxh1);
  float s2v = wsum64(dxh0 * xh0 + dxh1 * xh1);
  float g0 = x2.x + rs * (dxh0 - s1 * (1.0f / 128) - xh0 * (s2v * (1.0f / 128)));
  float g1 = x2.y + rs * (dxh1 - s1 * (1.0f / 128) - xh1 * (s2v * (1.0f / 128)));
  float gn = sqrtf(wsum64(g0 * g0 + g1 * g1));
  float gc = 1.0f / fmaxf(gn, 1.0f);
  g0 *= gc; g1 *= gc;
  float step = step_p[0];
  float xn0 = x2.x - step * g0, xn1 = x2.y - step * g1;
  float sn = sqrtf(wsum64(xn0 * xn0 + xn1 * xn1));
  float sc = 10.0f / fmaxf(sn, 10.0f);
  ((float2*)(out + (size_t)n * 128))[l] = make_float2(xn0 * sc, xn1 * sc);
  if (blockIdx.x == 0 && threadIdx.x < NG_G)
    out[(size_t)N_NODES * 128 + threadIdx.x] = Eg[threadIdx.x];
}

extern "C" void kernel_launch(void* const* d_in, const int* in_sizes, int n_in,
                              void* d_out, int out_size, void* d_ws, size_t ws_size,
                              hipStream_t stream) {
  const float* X     = (const float*)d_in[0];
  const int*  c_2    = (const int*) d_in[1];
  const int*  u_2    = (const int*) d_in[2];
  const int*  c_3    = (const int*) d_in[3];
  const int*  u_3    = (const int*) d_in[4];
  const int*  v_3    = (const int*) d_in[5];
  const int*  t_tau  = (const int*) d_in[6];
  const int*  batch  = (const int*) d_in[7];
  const float* a_2   = (const float*)d_in[8];
  const float* step_s= (const float*)d_in[9];
  const float* ln_g  = (const float*)d_in[10];
  const float* ln_b  = (const float*)d_in[11];
  const float* W_Q2  = (const float*)d_in[12];
  const float* W_K2  = (const float*)d_in[13];
  const float* W_Q3  = (const float*)d_in[14];
  const float* W_K3  = (const float*)d_in[15];
  const float* T_tau = (const float*)d_in[16];
  const float* W_Qm  = (const float*)d_in[17];
  const float* W_Km  = (const float*)d_in[18];
  const float* B_mem = (const float*)d_in[19];
  float* out = (float*)d_out;

  char* wb = (char*)d_ws;
  float* Wcat   = (float*)wb; wb += 768 * D_DIM * 4;
  float* Mprod  = (float*)wb; wb += 8192 * 4;
  float* mu     = (float*)wb; wb += N_NODES * 4;
  float* rstd   = (float*)wb; wb += N_NODES * 4;
  float* s2     = (float*)wb; wb += (size_t)E_EDG * 2 * 4;
  float* rz2    = (float*)wb; wb += N_NODES * 2 * 4;
  float* s3     = (float*)wb; wb += (size_t)M_MOT * 2 * 4;
  float* qkb    = (float*)wb; wb += (size_t)M_MOT * 4 * 4;
  float* tvb    = (float*)wb; wb += (size_t)M_MOT * 4 * 4;
  float* rz3    = (float*)wb; wb += N_NODES * 2 * 4;
  float* e_node = (float*)wb; wb += N_NODES * 4;
  float* e_pair = (float*)wb; wb += N_NODES * 4;
  float* e_mot  = (float*)wb; wb += N_NODES * 4;
  float* e_mem  = (float*)wb; wb += N_NODES * 4;
  float* Eg     = (float*)wb; wb += NG_G * 4;
  float* dG     = (float*)wb; wb += (size_t)N_NODES * D_DIM * 4;
  bf16* Gb      = (bf16*)wb;  wb += (size_t)N_NODES * D_DIM * 2;
  bf16* P       = (bf16*)wb;  wb += (size_t)N_NODES * F_TOT * 2;
  bf16* dP      = (bf16*)wb;  wb += (size_t)N_NODES * F_TOT * 2;
  bf16* wfF     = (bf16*)wb;  wb += 106496 * 2;
  bf16* wfB     = (bf16*)wb;  wb += 106496 * 2;
  bf16* Ttb     = (bf16*)wb;  wb += 8192 * 2;
  int* cntcur   = (int*)wb;   wb += 5 * N_NODES * 4;
  int* off      = (int*)wb;   wb += 5 * (N_NODES + 1) * 4;
  wb = (char*)(((size_t)wb + 15) & ~(size_t)15);
  uint2* lec    = (uint2*)wb; wb += (size_t)E_EDG * 8;
  uint2* leu    = (uint2*)wb; wb += (size_t)E_EDG * 8;
  uint2* lmc    = (uint2*)wb; wb += (size_t)M_MOT * 8;
  uint2* lmu    = (uint2*)wb; wb += (size_t)M_MOT * 8;
  uint2* lmv    = (uint2*)wb; wb += (size_t)M_MOT * 8;

  const int* off_ec = off;
  const int* off_eu = off + (N_NODES + 1);
  const int* off_mc = off + 2 * (N_NODES + 1);
  const int* off_mu = off + 3 * (N_NODES + 1);
  const int* off_mv = off + 4 * (N_NODES + 1);

  hipMemsetAsync(cntcur, 0, 5 * N_NODES * sizeof(int), stream);
  hipMemsetAsync(Eg, 0, NG_G * sizeof(float), stream);
  hipLaunchKernelGGL(k_phaseA, dim3(1504), dim3(256), 0, stream,
                     c_2, u_2, c_3, u_3, v_3, W_Q2, W_K2, W_Q3, W_K3,
                     W_Qm, W_Km, B_mem, T_tau, cntcur, Wcat, Ttb, Mprod);
  hipLaunchKernelGGL(k_phaseB, dim3(2157), dim3(1024), 0, stream,
                     cntcur, off, X, ln_g, ln_b, Gb, mu, rstd, e_node,
                     Wcat, Mprod, wfF, wfB);
  hipLaunchKernelGGL(k_phaseC, dim3(7680), dim3(256), 0, stream,
                     Gb, wfF, P, c_2, u_2, c_3, u_3, v_3, t_tau, a_2, cntcur,
                     lec, leu, lmc, lmu, lmv);
  hipLaunchKernelGGL(k_fused_c, dim3(3 * (N_NODES / 4)), dim3(256), 0, stream,
                     P, lec, lmc, Ttb, off_ec, off_mc,
                     s2, rz2, s3, qkb, tvb, rz3, dP, e_pair, e_mot, e_mem);
  hipLaunchKernelGGL(k_phaseE, dim3(640 + 2 * (N_NODES / 4)), dim3(256), 0, stream,
                     P, leu, lmu, lmv, Ttb, s2, rz2, s3, rz3, qkb, tvb,
                     off_eu, off_mu, off_mv, dP,
                     e_node, e_pair, e_mot, e_mem, batch, Eg, wfB, dG);
  hipLaunchKernelGGL(k_bwd2, dim3(N_NODES / 64), dim3(256), 0, stream, dP, wfB, dG);
  hipLaunchKernelGGL(k_finalize, dim3(N_NODES / 4), dim3(256), 0, stream,
                     X, dG, ln_g, mu, rstd, step_s, Eg, out);
}

// Round 13
// 379.254 us; speedup vs baseline: 1.2120x; 1.2120x over previous
//
#include <hip/hip_runtime.h>
#include <hip/hip_bf16.h>
#include <math.h>

typedef __hip_bfloat16 bf16;
typedef short bf16x8 __attribute__((ext_vector_type(8)));
typedef float f32x4 __attribute__((ext_vector_type(4)));

#define N_NODES 32768
#define D_DIM 128
#define E_EDG 262144
#define M_MOT 131072
#define NG_G 32
#define F_TOT 832
// P: Q2[0,128) K2[128,256) Q3[256,512) K3[512,768) S_mem[768,832)
// dP: dQ2 dK2 dQ3 dK3 Pm ; -0.125*Km@W_Qm folded into bwd B-frags
// lam2=1 lam3=0.5 lamm=1 b2=b3=bm=1 ; no-max softmax, z as reciprocal
// R13: revert R12's bwd-split-into-phaseE (VGPR 72 -> occupancy collapse);
//      keep quarter-wave edges + uint4 motifs + wave-per-node finalize.

__device__ __forceinline__ float wsum64(float v){
#pragma unroll
  for (int o = 32; o > 0; o >>= 1) v += __shfl_xor(v, o, 64);
  return v;
}
__device__ __forceinline__ float hsum32(float v){
#pragma unroll
  for (int o = 16; o > 0; o >>= 1) v += __shfl_xor(v, o, 64);
  return v;
}
__device__ __forceinline__ float hmax32(float v){
#pragma unroll
  for (int o = 16; o > 0; o >>= 1) v = fmaxf(v, __shfl_xor(v, o, 64));
  return v;
}
__device__ __forceinline__ float hsum8(float v){
#pragma unroll
  for (int o = 4; o > 0; o >>= 1) v += __shfl_xor(v, o, 64);
  return v;
}
__device__ __forceinline__ float bflo(unsigned u){ return __uint_as_float(u << 16); }
__device__ __forceinline__ float bfhi(unsigned u){ return __uint_as_float(u & 0xffff0000u); }
__device__ __forceinline__ unsigned packbf(float x, float y){
  bf16 a = __float2bfloat16(x), b = __float2bfloat16(y);
  unsigned short ua = *(unsigned short*)&a, ub = *(unsigned short*)&b;
  return (unsigned)ua | ((unsigned)ub << 16);
}
__device__ __forceinline__ void unpk8(uint4 p, float* f){
  f[0] = bflo(p.x); f[1] = bfhi(p.x); f[2] = bflo(p.y); f[3] = bfhi(p.y);
  f[4] = bflo(p.z); f[5] = bfhi(p.z); f[6] = bflo(p.w); f[7] = bfhi(p.w);
}

// ================ PHASE A: hist | Wcat/Ttb prep | Mprod (Km in LDS) ================
__global__ __launch_bounds__(256) void k_phaseA(
    const int* c2, const int* u2, const int* c3, const int* u3, const int* v3,
    const float* wq2, const float* wk2, const float* wq3, const float* wk3,
    const float* wqm, const float* wkm, const float* bmem, const float* Ttau,
    int* cnt, float* Wcat, bf16* Ttb, float* Mprod){
  __shared__ float KmL[64];
  int b = blockIdx.x, t = threadIdx.x;
  if (b < 1024){
    int i = b * 256 + t;
    atomicAdd(&cnt[c2[i]], 1);
    atomicAdd(&cnt[N_NODES + u2[i]], 1);
    if (i < M_MOT){
      atomicAdd(&cnt[2 * N_NODES + c3[i]], 1);
      atomicAdd(&cnt[3 * N_NODES + u3[i]], 1);
      atomicAdd(&cnt[4 * N_NODES + v3[i]], 1);
    }
  } else if (b < 1440){
    int idx = (b - 1024) * 256 + t;
    if (idx < 768 * D_DIM){
      int f = idx / D_DIM, d = idx - f * D_DIM;
      const float* src; int fr;
      if      (f < 128){ src = wq2; fr = f; }
      else if (f < 256){ src = wk2; fr = f - 128; }
      else if (f < 512){ src = wq3; fr = f - 256; }
      else             { src = wk3; fr = f - 512; }
      Wcat[f * D_DIM + d] = src[fr * D_DIM + d];
    } else {
      int j = idx - 768 * D_DIM; // < 8192
      Ttb[j] = __float2bfloat16(Ttau[j]);
    }
  } else {
    int hk = b - 1440;            // 0..63
    int h = hk >> 5, k = hk & 31;
    if (t < 64){
      const float* wrow = wkm + (size_t)(h * 64 + t) * D_DIM;
      const float* brow = bmem + k * D_DIM;
      float acc = 0.f;
      for (int d = 0; d < D_DIM; d++) acc += wrow[d] * brow[d];
      KmL[t] = acc;
    }
    __syncthreads();
    if (t < 128){
      const float* w = wqm + (size_t)(h * 64) * 128 + t;
      float acc = 0.f;
      for (int z = 0; z < 64; z++) acc += w[z * 128] * KmL[z];
      Mprod[t * 64 + hk] = acc;
    }
  }
}

// ================ PHASE B: scan | layernorm (wave/node) | pack_frags ================
__global__ __launch_bounds__(1024) void k_phaseB(
    int* cntcur, int* off,
    const float* X, const float* gamma, const float* beta,
    bf16* Gb, float* mu, float* rstd, float* e_node,
    const float* Wcat, const float* Mprod, bf16* wfF, bf16* wfB){
  __shared__ int sd[1024];
  int b = blockIdx.x, t = threadIdx.x;
  if (b < 5){
    int a = b;
    int* c = cntcur + a * N_NODES;
    int* o = off + a * (N_NODES + 1);
    int loc[32];
    int sum = 0;
#pragma unroll
    for (int j = 0; j < 32; j++){ loc[j] = sum; sum += c[t * 32 + j]; }
    sd[t] = sum;
    __syncthreads();
    for (int s = 1; s < 1024; s <<= 1){
      int v = (t >= s) ? sd[t - s] : 0;
      __syncthreads();
      sd[t] += v;
      __syncthreads();
    }
    int excl = sd[t] - sum;
#pragma unroll
    for (int j = 0; j < 32; j++){
      int val = excl + loc[j];
      o[t * 32 + j] = val;
      c[t * 32 + j] = val;
    }
    if (t == 1023) o[N_NODES] = sd[1023];
  } else if (b < 2053){
    int wv = t >> 6, l = t & 63;
    int n = (b - 5) * 16 + wv;
    float2 x2 = ((const float2*)(X + (size_t)n * 128))[l];
    float sumx = wsum64(x2.x + x2.y);
    float sumxx = wsum64(x2.x * x2.x + x2.y * x2.y);
    float m = sumx * (1.0f / 128.0f);
    float var = sumxx * (1.0f / 128.0f) - m * m;
    float rs = rsqrtf(var + 1e-5f);
    float2 gg = ((const float2*)gamma)[l];
    float2 bb = ((const float2*)beta)[l];
    ((unsigned*)(Gb + (size_t)n * 128))[l] =
        packbf(gg.x * (x2.x - m) * rs + bb.x, gg.y * (x2.y - m) * rs + bb.y);
    if (l == 0){ mu[n] = m; rstd[n] = rs; e_node[n] = 0.5f * sumxx; }
  } else {
    int idx = (b - 2053) * 1024 + t;   // < 106496
    int j = idx & 7, lane = (idx >> 3) & 63, tt = idx >> 9;
    {
      int tn = tt >> 2, kt = tt & 3;
      int f = tn * 16 + (lane & 15), d = kt * 32 + (lane >> 4) * 8 + j;
      float v = (f < 768) ? Wcat[f * 128 + d] : 0.125f * Mprod[d * 64 + (f - 768)];
      wfF[idx] = __float2bfloat16(v);
    }
    {
      int td = tt / 26, tf = tt - td * 26;
      int f = tf * 32 + (lane >> 4) * 8 + j, d = td * 16 + (lane & 15);
      float v = (f < 768) ? Wcat[f * 128 + d] : -0.125f * Mprod[d * 64 + (f - 768)];
      wfB[idx] = __float2bfloat16(v);
    }
  }
}

// ================ PHASE C: fwd_mfma (13/15) | fill (2/15) interleaved ================
__global__ __launch_bounds__(256) void k_phaseC(
    const bf16* Gb, const bf16* wfF, bf16* P,
    const int* c2, const int* u2, const int* c3, const int* u3, const int* v3,
    const int* tt, const float* a2, int* cur,
    uint2* lec, uint2* leu, uint2* lmc, uint2* lmu, uint2* lmv){
  int b = blockIdx.x;
  int g = b / 15, r = b - g * 15;
  if (r < 13){
    int f = g * 13 + r;
    int bx = f & 511, by = f >> 9;
    int wave = threadIdx.x >> 6, lane = threadIdx.x & 63;
    int m0 = bx * 64 + wave * 16;
    int tn0 = by * 4;
    int rw = lane & 15, quad = lane >> 4;
    const bf16* aptr = Gb + (size_t)(m0 + rw) * 128 + quad * 8;
    bf16x8 a[4];
#pragma unroll
    for (int kt = 0; kt < 4; kt++) a[kt] = *(const bf16x8*)(aptr + kt * 32);
    f32x4 acc[4];
#pragma unroll
    for (int i = 0; i < 4; i++) acc[i] = (f32x4){0.f, 0.f, 0.f, 0.f};
#pragma unroll
    for (int nf = 0; nf < 4; nf++){
      int tn = tn0 + nf;
#pragma unroll
      for (int kt = 0; kt < 4; kt++){
        bf16x8 bb = *(const bf16x8*)(wfF + (((size_t)tn * 4 + kt) * 64 + lane) * 8);
        acc[nf] = __builtin_amdgcn_mfma_f32_16x16x32_bf16(a[kt], bb, acc[nf], 0, 0, 0);
      }
    }
#pragma unroll
    for (int nf = 0; nf < 4; nf++){
      int col = (tn0 + nf) * 16 + rw;
#pragma unroll
      for (int rr = 0; rr < 4; rr++){
        int row = m0 + quad * 4 + rr;
        P[(size_t)row * F_TOT + col] = __float2bfloat16(acc[nf][rr]);
      }
    }
  } else {
    int i = (g * 2 + (r - 13)) * 256 + threadIdx.x;
    {
      int c = c2[i], u = u2[i];
      int posc = atomicAdd(&cur[c], 1);
      float2 av = *(const float2*)(a2 + (size_t)i * 2);
      lec[posc] = make_uint2((unsigned)u, packbf(av.x, av.y));
      int posu = atomicAdd(&cur[N_NODES + u], 1);
      leu[posu] = make_uint2((unsigned)c, (unsigned)posc);
    }
    if (i < M_MOT){
      int c = c3[i], u = u3[i], v = v3[i], t = tt[i];
      int posc = atomicAdd(&cur[2 * N_NODES + c], 1);
      lmc[posc] = make_uint2((unsigned)(u | (v << 16)), (unsigned)t);
      int posu = atomicAdd(&cur[3 * N_NODES + u], 1);
      lmu[posu] = make_uint2((unsigned)c, (unsigned)posc);
      int posv = atomicAdd(&cur[4 * N_NODES + v], 1);
      lmv[posv] = make_uint2((unsigned)(c | (t << 16)), (unsigned)posc);
    }
  }
}

// ================ PHASE D: fused forward gathers ================
__global__ __launch_bounds__(256) void k_fused_c(const bf16* P, const uint2* lec, const uint2* lmc,
                   const bf16* Ttb, const int* off_ec, const int* off_mc,
                   float* s2, float* rz2, float* s3, float* qkb, float* tvb, float* rz3,
                   bf16* dP, float* e_pair, float* e_mot, float* e_mem){
  int b = blockIdx.x;
  int type = b % 3, grp = b / 3;
  int wave = threadIdx.x >> 6, z = threadIdx.x & 63;
  int n = grp * 4 + wave;
  int l = z & 31, lh = z >> 5;

  if (type == 0){
    // ---- edges: 4 per wave (16-lane groups), 8-lane head sub-groups ----
    int q = z >> 4, l16 = z & 15, hg = l16 >> 3;
    int beg = off_ec[n], end = off_ec[n + 1];
    uint4 qp = ((const uint4*)(P + (size_t)n * F_TOT))[l16];
    float qv[8]; unpk8(qp, qv);
    float acc[8] = {0,0,0,0,0,0,0,0};
    float zz = 0.f;
    int iters = (end - beg + 3) >> 2;
    for (int it = 0; it < iters; it++){
      int idx = beg + 4 * it + q;
      bool valid = idx < end;
      int idc = valid ? idx : end - 1;
      uint2 pl = lec[idc];
      uint4 kp = ((const uint4*)(P + (size_t)pl.x * F_TOT + 128))[l16];
      float kv[8]; unpk8(kp, kv);
      float d = 0.f;
#pragma unroll
      for (int j = 0; j < 8; j++) d += qv[j] * kv[j];
      float s = hsum8(d) * 0.125f + (hg ? bfhi(pl.y) : bflo(pl.y));
      if (valid && (l16 & 7) == 0) s2[2 * idx + hg] = s;
      float ex = valid ? expf(s) : 0.f;
#pragma unroll
      for (int j = 0; j < 8; j++) acc[j] += ex * kv[j];
      zz += ex;
    }
#pragma unroll
    for (int j = 0; j < 8; j++){
      acc[j] += __shfl_xor(acc[j], 16, 64);
      acc[j] += __shfl_xor(acc[j], 32, 64);
    }
    zz += __shfl_xor(zz, 16, 64);
    zz += __shfl_xor(zz, 32, 64);
    float rz = (zz > 0.f) ? 1.0f / zz : 0.f;
    float coef = -0.125f * rz;
    if (z < 16){
      uint4 o;
      o.x = packbf(coef * acc[0], coef * acc[1]);
      o.y = packbf(coef * acc[2], coef * acc[3]);
      o.z = packbf(coef * acc[4], coef * acc[5]);
      o.w = packbf(coef * acc[6], coef * acc[7]);
      ((uint4*)(dP + (size_t)n * F_TOT))[l16] = o;
      if ((l16 & 7) == 0) rz2[n * 2 + hg] = rz;
    }
    float eterm = (zz > 0.f) ? -logf(zz) : 0.f;   // lam2 = 1
    float eo = __shfl(eterm, 8, 64);
    if (z == 0) e_pair[n] = eterm + eo;
  } else if (type == 1){
    // ---- motifs: 2 per wave (32-lane halves), 8-lane hr groups ----
    int g = l >> 3, hg = g >> 1;
    int beg = off_mc[n], end = off_mc[n + 1];
    uint4 qp = ((const uint4*)(P + (size_t)n * F_TOT + 256))[l];
    float qv[8]; unpk8(qp, qv);
    float acc[8] = {0,0,0,0,0,0,0,0};
    float zz = 0.f;
    int iters = (end - beg + 1) >> 1;
    for (int it = 0; it < iters; it++){
      int idx = beg + 2 * it + lh;
      bool valid = idx < end;
      int idc = valid ? idx : end - 1;
      uint2 pl = lmc[idc];
      int u = pl.x & 0xffff, v = pl.x >> 16, t = pl.y;
      uint4 kup = ((const uint4*)(P + (size_t)u * F_TOT + 512))[l];
      uint4 kvp = ((const uint4*)(P + (size_t)v * F_TOT + 512))[l];
      uint4 tp  = ((const uint4*)(Ttb + (size_t)t * 256))[l];
      float k[8], vv[8], pt[8];
      unpk8(kup, k); unpk8(kvp, vv); unpk8(tp, pt);
      float dq = 0.f, dt = 0.f;
#pragma unroll
      for (int j = 0; j < 8; j++){ dq += qv[j] * k[j]; dt += pt[j] * vv[j]; }
      float qk = hsum8(dq);
      float tv = hsum8(dt);
      if (valid && (l & 7) == 0){ qkb[(size_t)4 * idx + g] = qk; tvb[(size_t)4 * idx + g] = tv; }
      float w = qk * tv;
      float s = (w + __shfl_xor(w, 8, 64)) * (1.0f / 64.0f);
      if (valid && (l & 15) == 0) s3[2 * idx + hg] = s;
      float ex = valid ? expf(s) : 0.f;
      float et = ex * tv;
#pragma unroll
      for (int j = 0; j < 8; j++) acc[j] += et * k[j];
      zz += ex;
    }
#pragma unroll
    for (int j = 0; j < 8; j++) acc[j] += __shfl_xor(acc[j], 32, 64);
    zz += __shfl_xor(zz, 32, 64);
    float rz = (zz > 0.f) ? 1.0f / zz : 0.f;
    float coef = (-0.5f / 64.0f) * rz;
    if (z < 32){
      uint4 o;
      o.x = packbf(coef * acc[0], coef * acc[1]);
      o.y = packbf(coef * acc[2], coef * acc[3]);
      o.z = packbf(coef * acc[4], coef * acc[5]);
      o.w = packbf(coef * acc[6], coef * acc[7]);
      ((uint4*)(dP + (size_t)n * F_TOT + 256))[l] = o;
      if ((l & 15) == 0) rz3[n * 2 + hg] = rz;
    }
    float eterm = (zz > 0.f) ? -0.5f * logf(zz) : 0.f;   // lam3 = 0.5
    float eo = __shfl(eterm, 16, 64);
    if (z == 0) e_mot[n] = eterm + eo;
  } else {
    unsigned short us = ((const unsigned short*)(P + (size_t)n * F_TOT + 768))[z];
    float s = __uint_as_float((unsigned)us << 16);
    float mx = hmax32(s);
    float ex = expf(s - mx);
    float se = hsum32(ex);
    float p = ex / se;
    bf16 pb = __float2bfloat16(p);
    ((unsigned short*)(dP + (size_t)n * F_TOT + 768))[z] = *(unsigned short*)&pb;
    float eterm = -(mx + logf(se));
    float eo = __shfl(eterm, z ^ 32, 64);
    if (z == 0) e_mem[n] = eterm + eo;   // lamm=1, bm=1
  }
}

// ================ PHASE E: node_energy (128) | fused_uv ================
__global__ __launch_bounds__(256) void k_phaseE(const bf16* P, const uint2* leu,
                    const uint2* lmu, const uint2* lmv, const bf16* Ttb,
                    const float* s2, const float* rz2, const float* s3, const float* rz3,
                    const float* qkb, const float* tvb,
                    const int* off_eu, const int* off_mu, const int* off_mv, bf16* dP,
                    const float* e_node, const float* e_pair, const float* e_mot,
                    const float* e_mem, const int* batch, float* Eg){
  __shared__ float eg[NG_G];
  int b = blockIdx.x;
  if (b < 128){
    int t = threadIdx.x;
    if (t < NG_G) eg[t] = 0.f;
    __syncthreads();
    int n = b * 256 + t;
    float e = e_node[n] + e_pair[n] + e_mot[n] + e_mem[n];
    atomicAdd(&eg[batch[n]], e);
    __syncthreads();
    if (t < NG_G) atomicAdd(&Eg[t], eg[t]);
    return;
  }
  int b2 = b - 128;
  int type = b2 & 1, grp = b2 >> 1;
  int wave = threadIdx.x >> 6, z = threadIdx.x & 63;
  int n = grp * 4 + wave;
  int l = z & 31, lh = z >> 5;

  if (type == 0){
    // dK2[u]: 4 edges per wave
    int q = z >> 4, l16 = z & 15, hg = l16 >> 3;
    int beg = off_eu[n], end = off_eu[n + 1];
    float acc[8] = {0,0,0,0,0,0,0,0};
    int iters = (end - beg + 3) >> 2;
    for (int it = 0; it < iters; it++){
      int idx = beg + 4 * it + q;
      bool valid = idx < end;
      int idc = valid ? idx : end - 1;
      uint2 pl = leu[idc];
      uint4 qp = ((const uint4*)(P + (size_t)pl.x * F_TOT))[l16];
      float qv[8]; unpk8(qp, qv);
      float p = valid ? expf(s2[2 * pl.y + hg]) * rz2[pl.x * 2 + hg] : 0.f;
#pragma unroll
      for (int j = 0; j < 8; j++) acc[j] += p * qv[j];
    }
#pragma unroll
    for (int j = 0; j < 8; j++){
      acc[j] += __shfl_xor(acc[j], 16, 64);
      acc[j] += __shfl_xor(acc[j], 32, 64);
    }
    if (z < 16){
      uint4 o;
      o.x = packbf(-0.125f * acc[0], -0.125f * acc[1]);
      o.y = packbf(-0.125f * acc[2], -0.125f * acc[3]);
      o.z = packbf(-0.125f * acc[4], -0.125f * acc[5]);
      o.w = packbf(-0.125f * acc[6], -0.125f * acc[7]);
      ((uint4*)(dP + (size_t)n * F_TOT + 128))[l16] = o;
    }
  } else {
    int g = l >> 3, hg = g >> 1;
    float acc[8] = {0,0,0,0,0,0,0,0};
    {
      int beg = off_mu[n], end = off_mu[n + 1];
      int iters = (end - beg + 1) >> 1;
      for (int it = 0; it < iters; it++){
        int idx = beg + 2 * it + lh;
        bool valid = idx < end;
        int idc = valid ? idx : end - 1;
        uint2 pl = lmu[idc];
        unsigned c = pl.x, posc = pl.y;
        uint4 qp = ((const uint4*)(P + (size_t)c * F_TOT + 256))[l];
        float qv[8]; unpk8(qp, qv);
        float w = valid ? expf(s3[2 * posc + hg]) * rz3[c * 2 + hg] * tvb[(size_t)4 * posc + g] : 0.f;
#pragma unroll
        for (int j = 0; j < 8; j++) acc[j] += w * qv[j];
      }
    }
    {
      int beg = off_mv[n], end = off_mv[n + 1];
      int iters = (end - beg + 1) >> 1;
      for (int it = 0; it < iters; it++){
        int idx = beg + 2 * it + lh;
        bool valid = idx < end;
        int idc = valid ? idx : end - 1;
        uint2 pl = lmv[idc];
        unsigned c = pl.x & 0xffff, t = pl.x >> 16, posc = pl.y;
        uint4 tp = ((const uint4*)(Ttb + (size_t)t * 256))[l];
        float pt[8]; unpk8(tp, pt);
        float w = valid ? expf(s3[2 * posc + hg]) * rz3[c * 2 + hg] * qkb[(size_t)4 * posc + g] : 0.f;
#pragma unroll
        for (int j = 0; j < 8; j++) acc[j] += w * pt[j];
      }
    }
#pragma unroll
    for (int j = 0; j < 8; j++) acc[j] += __shfl_xor(acc[j], 32, 64);
    const float cst = -0.5f / 64.0f;
    if (z < 32){
      uint4 o;
      o.x = packbf(cst * acc[0], cst * acc[1]);
      o.y = packbf(cst * acc[2], cst * acc[3]);
      o.z = packbf(cst * acc[4], cst * acc[5]);
      o.w = packbf(cst * acc[6], cst * acc[7]);
      ((uint4*)(dP + (size_t)n * F_TOT + 512))[l] = o;
    }
  }
}

// ================ PHASE F: bwd GEMM via MFMA (full 26 K-tiles) ================
__global__ __launch_bounds__(256) void k_bwd_mfma(const bf16* dP, const bf16* wfB, float* dG){
  int wave = threadIdx.x >> 6, lane = threadIdx.x & 63;
  int m0 = blockIdx.x * 64 + wave * 16;
  int rw = lane & 15, quad = lane >> 4;
  const bf16* aptr = dP + (size_t)(m0 + rw) * F_TOT + quad * 8;
  f32x4 acc[8];
#pragma unroll
  for (int i = 0; i < 8; i++) acc[i] = (f32x4){0.f, 0.f, 0.f, 0.f};
  for (int kt = 0; kt < 26; kt++){
    bf16x8 a = *(const bf16x8*)(aptr + kt * 32);
#pragma unroll
    for (int td = 0; td < 8; td++){
      bf16x8 b = *(const bf16x8*)(wfB + (((size_t)td * 26 + kt) * 64 + lane) * 8);
      acc[td] = __builtin_amdgcn_mfma_f32_16x16x32_bf16(a, b, acc[td], 0, 0, 0);
    }
  }
#pragma unroll
  for (int td = 0; td < 8; td++){
    int col = td * 16 + rw;
#pragma unroll
    for (int r = 0; r < 4; r++){
      int row = m0 + quad * 4 + r;
      dG[(size_t)row * 128 + col] = acc[td][r];
    }
  }
}

// ================ PHASE G: finalize (wave/node) + Eg write ================
__global__ __launch_bounds__(256) void k_finalize(const float* X, const float* dG, const float* gamma,
                    const float* mu, const float* rstd, const float* step_p,
                    const float* Eg, float* out){
  int wave = threadIdx.x >> 6, l = threadIdx.x & 63;
  int n = blockIdx.x * 4 + wave;
  float2 x2 = ((const float2*)(X + (size_t)n * 128))[l];
  float2 dg2 = ((const float2*)(dG + (size_t)n * 128))[l];
  float2 gg = ((const float2*)gamma)[l];
  float rs = rstd[n], m = mu[n];
  float xh0 = (x2.x - m) * rs, xh1 = (x2.y - m) * rs;
  float dxh0 = dg2.x * gg.x, dxh1 = dg2.y * gg.y;
  float s1 = wsum64(dxh0 + dxh1);
  float s2v = wsum64(dxh0 * xh0 + dxh1 * xh1);
  float g0 = x2.x + rs * (dxh0 - s1 * (1.0f / 128) - xh0 * (s2v * (1.0f / 128)));
  float g1 = x2.y + rs * (dxh1 - s1 * (1.0f / 128) - xh1 * (s2v * (1.0f / 128)));
  float gn = sqrtf(wsum64(g0 * g0 + g1 * g1));
  float gc = 1.0f / fmaxf(gn, 1.0f);
  g0 *= gc; g1 *= gc;
  float step = step_p[0];
  float xn0 = x2.x - step * g0, xn1 = x2.y - step * g1;
  float sn = sqrtf(wsum64(xn0 * xn0 + xn1 * xn1));
  float sc = 10.0f / fmaxf(sn, 10.0f);
  ((float2*)(out + (size_t)n * 128))[l] = make_float2(xn0 * sc, xn1 * sc);
  if (blockIdx.x == 0 && threadIdx.x < NG_G)
    out[(size_t)N_NODES * 128 + threadIdx.x] = Eg[threadIdx.x];
}

extern "C" void kernel_launch(void* const* d_in, const int* in_sizes, int n_in,
                              void* d_out, int out_size, void* d_ws, size_t ws_size,
                              hipStream_t stream) {
  const float* X     = (const float*)d_in[0];
  const int*  c_2    = (const int*) d_in[1];
  const int*  u_2    = (const int*) d_in[2];
  const int*  c_3    = (const int*) d_in[3];
  const int*  u_3    = (const int*) d_in[4];
  const int*  v_3    = (const int*) d_in[5];
  const int*  t_tau  = (const int*) d_in[6];
  const int*  batch  = (const int*) d_in[7];
  const float* a_2   = (const float*)d_in[8];
  const float* step_s= (const float*)d_in[9];
  const float* ln_g  = (const float*)d_in[10];
  const float* ln_b  = (const float*)d_in[11];
  const float* W_Q2  = (const float*)d_in[12];
  const float* W_K2  = (const float*)d_in[13];
  const float* W_Q3  = (const float*)d_in[14];
  const float* W_K3  = (const float*)d_in[15];
  const float* T_tau = (const float*)d_in[16];
  const float* W_Qm  = (const float*)d_in[17];
  const float* W_Km  = (const float*)d_in[18];
  const float* B_mem = (const float*)d_in[19];
  float* out = (float*)d_out;

  char* wb = (char*)d_ws;
  float* Wcat   = (float*)wb; wb += 768 * D_DIM * 4;
  float* Mprod  = (float*)wb; wb += 8192 * 4;
  float* mu     = (float*)wb; wb += N_NODES * 4;
  float* rstd   = (float*)wb; wb += N_NODES * 4;
  float* s2     = (float*)wb; wb += (size_t)E_EDG * 2 * 4;
  float* rz2    = (float*)wb; wb += N_NODES * 2 * 4;
  float* s3     = (float*)wb; wb += (size_t)M_MOT * 2 * 4;
  float* qkb    = (float*)wb; wb += (size_t)M_MOT * 4 * 4;
  float* tvb    = (float*)wb; wb += (size_t)M_MOT * 4 * 4;
  float* rz3    = (float*)wb; wb += N_NODES * 2 * 4;
  float* e_node = (float*)wb; wb += N_NODES * 4;
  float* e_pair = (float*)wb; wb += N_NODES * 4;
  float* e_mot  = (float*)wb; wb += N_NODES * 4;
  float* e_mem  = (float*)wb; wb += N_NODES * 4;
  float* Eg     = (float*)wb; wb += NG_G * 4;
  float* dG     = (float*)wb; wb += (size_t)N_NODES * D_DIM * 4;
  bf16* Gb      = (bf16*)wb;  wb += (size_t)N_NODES * D_DIM * 2;
  bf16* P       = (bf16*)wb;  wb += (size_t)N_NODES * F_TOT * 2;
  bf16* dP      = (bf16*)wb;  wb += (size_t)N_NODES * F_TOT * 2;
  bf16* wfF     = (bf16*)wb;  wb += 106496 * 2;
  bf16* wfB     = (bf16*)wb;  wb += 106496 * 2;
  bf16* Ttb     = (bf16*)wb;  wb += 8192 * 2;
  int* cntcur   = (int*)wb;   wb += 5 * N_NODES * 4;
  int* off      = (int*)wb;   wb += 5 * (N_NODES + 1) * 4;
  wb = (char*)(((size_t)wb + 15) & ~(size_t)15);
  uint2* lec    = (uint2*)wb; wb += (size_t)E_EDG * 8;
  uint2* leu    = (uint2*)wb; wb += (size_t)E_EDG * 8;
  uint2* lmc    = (uint2*)wb; wb += (size_t)M_MOT * 8;
  uint2* lmu    = (uint2*)wb; wb += (size_t)M_MOT * 8;
  uint2* lmv    = (uint2*)wb; wb += (size_t)M_MOT * 8;

  const int* off_ec = off;
  const int* off_eu = off + (N_NODES + 1);
  const int* off_mc = off + 2 * (N_NODES + 1);
  const int* off_mu = off + 3 * (N_NODES + 1);
  const int* off_mv = off + 4 * (N_NODES + 1);

  hipMemsetAsync(cntcur, 0, 5 * N_NODES * sizeof(int), stream);
  hipMemsetAsync(Eg, 0, NG_G * sizeof(float), stream);
  hipLaunchKernelGGL(k_phaseA, dim3(1504), dim3(256), 0, stream,
                     c_2, u_2, c_3, u_3, v_3, W_Q2, W_K2, W_Q3, W_K3,
                     W_Qm, W_Km, B_mem, T_tau, cntcur, Wcat, Ttb, Mprod);
  hipLaunchKernelGGL(k_phaseB, dim3(2157), dim3(1024), 0, stream,
                     cntcur, off, X, ln_g, ln_b, Gb, mu, rstd, e_node,
                     Wcat, Mprod, wfF, wfB);
  hipLaunchKernelGGL(k_phaseC, dim3(7680), dim3(256), 0, stream,
                     Gb, wfF, P, c_2, u_2, c_3, u_3, v_3, t_tau, a_2, cntcur,
                     lec, leu, lmc, lmu, lmv);
  hipLaunchKernelGGL(k_fused_c, dim3(3 * (N_NODES / 4)), dim3(256), 0, stream,
                     P, lec, lmc, Ttb, off_ec, off_mc,
                     s2, rz2, s3, qkb, tvb, rz3, dP, e_pair, e_mot, e_mem);
  hipLaunchKernelGGL(k_phaseE, dim3(128 + 2 * (N_NODES / 4)), dim3(256), 0, stream,
                     P, leu, lmu, lmv, Ttb, s2, rz2, s3, rz3, qkb, tvb,
                     off_eu, off_mu, off_mv, dP,
                     e_node, e_pair, e_mot, e_mem, batch, Eg);
  hipLaunchKernelGGL(k_bwd_mfma, dim3(N_NODES / 64), dim3(256), 0, stream, dP, wfB, dG);
  hipLaunchKernelGGL(k_finalize, dim3(N_NODES / 4), dim3(256), 0, stream,
                     X, dG, ln_g, mu, rstd, step_s, Eg, out);
}